// Round 12
// baseline (395.940 us; speedup 1.0000x reference)
//
#include <hip/hip_runtime.h>
#include <cstdint>
#include <cstddef>

#define N_NODES 100000
#define N_EDGES 1600000
#define N_GRAPHS 256
#define HID 128
#define NCLASS 8
#define MAXD 128
#define GEMM_GRID 1563  // ONE 64-node tile per block (A/B vs r10's 782: grid is the only change)

#define SCHUNK 2048
#define SNB ((N_NODES + SCHUNK - 1) / SCHUNK)  // 49

typedef short bf16x8 __attribute__((ext_vector_type(8)));
typedef float f32x4 __attribute__((ext_vector_type(4)));

static __device__ __forceinline__ float lrelu(float x) { return x >= 0.f ? x : 0.2f * x; }
static __device__ __forceinline__ float elu_f(float x) { return x > 0.f ? x : expm1f(x); }
static __device__ __forceinline__ unsigned f2bf(float x) {  // RNE bf16 (as uint16 in low bits)
    union { float f; unsigned u; } v; v.f = x;
    return (v.u + 0x7FFFu + ((v.u >> 16) & 1u)) >> 16;
}
static __device__ __forceinline__ float bf_lo(unsigned u) { return __uint_as_float(u << 16); }
static __device__ __forceinline__ float bf_hi(unsigned u) { return __uint_as_float(u & 0xFFFF0000u); }

// --- K1: cl1 = W1·al1, cr1 = W1·ar1 (layer-1 rank-1 collapse) ---
__global__ void k_prep(const float* __restrict__ W1, const float* __restrict__ al1,
                       const float* __restrict__ ar1, float* __restrict__ scal) {
    int l = threadIdx.x;  // 64 threads
    float pl = W1[l] * al1[l] + W1[l + 64] * al1[l + 64];
    float pr = W1[l] * ar1[l] + W1[l + 64] * ar1[l + 64];
    for (int m = 32; m >= 1; m >>= 1) { pl += __shfl_xor(pl, m); pr += __shfl_xor(pr, m); }
    if (l == 0) { scal[0] = pl; scal[1] = pr; }
}

// --- K2: degree count into 8 privatized replicas + per-edge rank (ONE atomic pass) ---
__global__ void k_degrank(const int* __restrict__ dst, int* __restrict__ dr,
                          int* __restrict__ rank) {
    int i = blockIdx.x * blockDim.x + threadIdx.x;
    int st = gridDim.x * blockDim.x;
    for (; i < N_EDGES; i += st) {
        int cls = (i >> 8) & (NCLASS - 1);
        rank[i] = atomicAdd(&dr[cls * N_NODES + dst[i]], 1);
    }
}

// --- K2b: total degree = sum of replicas ---
__global__ void k_sum(const int* __restrict__ dr, int* __restrict__ deg) {
    int d = blockIdx.x * blockDim.x + threadIdx.x;
    if (d < N_NODES) {
        int s = 0;
#pragma unroll
        for (int r = 0; r < NCLASS; r++) s += dr[r * N_NODES + d];
        deg[d] = s;
    }
}

// --- K3: exclusive scan of deg -> offsets ---
__global__ void k_scan_part(const int* __restrict__ deg, int* __restrict__ P) {
    __shared__ int sh[256];
    int base = blockIdx.x * SCHUNK + threadIdx.x * 8;
    int s = 0;
#pragma unroll
    for (int e = 0; e < 8; e++) { int idx = base + e; if (idx < N_NODES) s += deg[idx]; }
    sh[threadIdx.x] = s; __syncthreads();
    for (int d = 128; d >= 1; d >>= 1) {
        if (threadIdx.x < d) sh[threadIdx.x] += sh[threadIdx.x + d];
        __syncthreads();
    }
    if (threadIdx.x == 0) P[blockIdx.x] = sh[0];
}

__global__ void k_scan_p2(const int* __restrict__ P, int* __restrict__ P2, int* __restrict__ offs) {
    if (threadIdx.x == 0) {
        int run = 0;
        for (int b = 0; b < SNB; b++) { P2[b] = run; run += P[b]; }
        offs[N_NODES] = run;
    }
}

__global__ void k_scan_final(const int* __restrict__ deg, const int* __restrict__ P2,
                             int* __restrict__ offs) {
    __shared__ int sh[256];
    int base = blockIdx.x * SCHUNK + threadIdx.x * 8;
    int loc[8]; int s = 0;
#pragma unroll
    for (int e = 0; e < 8; e++) {
        int idx = base + e;
        loc[e] = (idx < N_NODES) ? deg[idx] : 0;
        s += loc[e];
    }
    int own = s;
    sh[threadIdx.x] = s; __syncthreads();
    for (int d = 1; d < 256; d <<= 1) {
        int v = (threadIdx.x >= (unsigned)d) ? sh[threadIdx.x - d] : 0;
        __syncthreads();
        sh[threadIdx.x] += v;
        __syncthreads();
    }
    int run = P2[blockIdx.x] + sh[threadIdx.x] - own;
#pragma unroll
    for (int e = 0; e < 8; e++) {
        int idx = base + e;
        if (idx < N_NODES) { offs[idx] = run; run += loc[e]; }
    }
}

// --- K3b: per-class base offsets ---
__global__ void k_base(const int* __restrict__ dr, const int* __restrict__ offs,
                       int* __restrict__ base) {
    int d = blockIdx.x * blockDim.x + threadIdx.x;
    if (d < N_NODES) {
        int run = offs[d];
#pragma unroll
        for (int r = 0; r < NCLASS; r++) { base[r * N_NODES + d] = run; run += dr[r * N_NODES + d]; }
    }
}

// --- K4: CSR fill — NO atomics ---
__global__ void k_fill(const int* __restrict__ src, const int* __restrict__ dst,
                       const int* __restrict__ base, const int* __restrict__ rank,
                       int* __restrict__ csr) {
    int i = blockIdx.x * blockDim.x + threadIdx.x;
    int st = gridDim.x * blockDim.x;
    for (; i < N_EDGES; i += st) {
        int cls = (i >> 8) & (NCLASS - 1);
        int pos = base[cls * N_NODES + dst[i]] + rank[i];
        csr[pos] = src[i];
    }
}

// --- K5: layer-1 attention -> t[i] (wave per node, lane-parallel edges) ---
__global__ __launch_bounds__(256) void k_l1(const int* __restrict__ deg, const int* __restrict__ offs,
                                            const int* __restrict__ csr_src, const float* __restrict__ scal,
                                            float* __restrict__ t) {
    int node = blockIdx.x * 4 + (threadIdx.x >> 6);
    if (node >= N_NODES) return;
    int l = threadIdx.x & 63;
    float cl = scal[0], cr = scal[1];
    float eri = cr * (float)deg[node];
    int off = offs[node], end = offs[node + 1];
    float m = -INFINITY, den = 0.f, num = 0.f;
    for (int e = off + l; e < end; e += 64) {
        int s = csr_src[e];
        float ds = (float)deg[s];
        float e1 = lrelu(cl * ds + eri);
        if (e1 > m) { float c = __expf(m - e1); den *= c; num *= c; m = e1; }
        float w = __expf(e1 - m);
        den += w; num += w * ds;
    }
    for (int st = 1; st < 64; st <<= 1) {
        float mo = __shfl_xor(m, st);
        float dn = __shfl_xor(den, st);
        float no = __shfl_xor(num, st);
        float mn = fmaxf(m, mo);
        float sa = (m  > -1e37f) ? __expf(m  - mn) : 0.f;
        float sb = (mo > -1e37f) ? __expf(mo - mn) : 0.f;
        den = den * sa + dn * sb;
        num = num * sa + no * sb;
        m = mn;
    }
    if (l == 0) t[node] = num / fmaxf(den, 1e-9f);
}

// --- K6: z2 = elu(t*W1+b1) @ W2 via bf16 MFMA 16x16x32 ---
// ONE tile per block (grid 1563). Epilogue: zt LDS stripe + coalesced full-line
// dwordx4 flush. Identical to r10 except grid/loop trip count.
__global__ __launch_bounds__(256, 3) void k_gemm(
    const float* __restrict__ t, const float* __restrict__ W1, const float* __restrict__ b1,
    const float* __restrict__ W2, const float* __restrict__ al2, const float* __restrict__ ar2,
    unsigned* __restrict__ zb, float* __restrict__ el2, float* __restrict__ er2) {
    __shared__ unsigned short W2t[HID * HID];  // 32KB bf16 [col][k], swizzled
    __shared__ unsigned zt[64][68];            // 17.4KB z-tile staging (stride 68: 16B-aligned)
    __shared__ float W1s[HID], b1s[HID], al2s[HID], ar2s[HID];
    int tid = threadIdx.x;
    if (tid < HID) {
        W1s[tid] = W1[tid]; b1s[tid] = b1[tid];
        al2s[tid] = al2[tid]; ar2s[tid] = ar2[tid];
    }
    const float4* W2v = (const float4*)W2;
    for (int q = tid; q < HID * HID / 4; q += 256) {
        int k = q >> 5;           // W2 row
        int c0 = (q & 31) << 2;   // col base
        float4 w = W2v[q];
        W2t[((c0 + 0) * HID + k) ^ (((c0 + 0) & 7) << 3)] = (unsigned short)f2bf(w.x);
        W2t[((c0 + 1) * HID + k) ^ (((c0 + 1) & 7) << 3)] = (unsigned short)f2bf(w.y);
        W2t[((c0 + 2) * HID + k) ^ (((c0 + 2) & 7) << 3)] = (unsigned short)f2bf(w.z);
        W2t[((c0 + 3) * HID + k) ^ (((c0 + 3) & 7) << 3)] = (unsigned short)f2bf(w.w);
    }
    __syncthreads();
    int wid = tid >> 6, lane = tid & 63;
    int nl = lane & 15;   // node-local row / col-local
    int kq = lane >> 4;   // k-quarter
    for (int i0 = blockIdx.x * 64; i0 < N_NODES; i0 += gridDim.x * 64) {
        int node = i0 + wid * 16 + nl;
        float tval = (node < N_NODES) ? t[node] : 0.f;
        f32x4 acc[8];
#pragma unroll
        for (int c = 0; c < 8; c++) acc[c] = (f32x4){0.f, 0.f, 0.f, 0.f};
#pragma unroll
        for (int s = 0; s < 4; s++) {
            int kb = s * 32 + kq * 8;
            float4 wa = *(const float4*)&W1s[kb];
            float4 wb = *(const float4*)&W1s[kb + 4];
            float4 ba = *(const float4*)&b1s[kb];
            float4 bb = *(const float4*)&b1s[kb + 4];
            float h0 = elu_f(tval * wa.x + ba.x);
            float h1 = elu_f(tval * wa.y + ba.y);
            float h2 = elu_f(tval * wa.z + ba.z);
            float h3 = elu_f(tval * wa.w + ba.w);
            float h4 = elu_f(tval * wb.x + bb.x);
            float h5 = elu_f(tval * wb.y + bb.y);
            float h6 = elu_f(tval * wb.z + bb.z);
            float h7 = elu_f(tval * wb.w + bb.w);
            union { unsigned u[4]; bf16x8 v; } afr;
            afr.u[0] = f2bf(h0) | (f2bf(h1) << 16);
            afr.u[1] = f2bf(h2) | (f2bf(h3) << 16);
            afr.u[2] = f2bf(h4) | (f2bf(h5) << 16);
            afr.u[3] = f2bf(h6) | (f2bf(h7) << 16);
#pragma unroll
            for (int c = 0; c < 8; c++) {
                int col = c * 16 + nl;
                int idx = (col * HID + kb) ^ ((col & 7) << 3);
                bf16x8 bfr = *(const bf16x8*)&W2t[idx];
                acc[c] = __builtin_amdgcn_mfma_f32_16x16x32_bf16(afr.v, bfr, acc[c], 0, 0, 0);
            }
        }
        // epilogue: el2/er2 from f32 acc
        int rnode = i0 + wid * 16 + kq * 4;
        float plv[4] = {0.f, 0.f, 0.f, 0.f}, prv[4] = {0.f, 0.f, 0.f, 0.f};
#pragma unroll
        for (int c = 0; c < 8; c++) {
            float av = al2s[c * 16 + nl], rv = ar2s[c * 16 + nl];
#pragma unroll
            for (int r = 0; r < 4; r++) {
                plv[r] += acc[c][r] * av;
                prv[r] += acc[c][r] * rv;
            }
        }
#pragma unroll
        for (int r = 0; r < 4; r++) {
#pragma unroll
            for (int m = 1; m < 16; m <<= 1) {
                plv[r] += __shfl_xor(plv[r], m);
                prv[r] += __shfl_xor(prv[r], m);
            }
        }
        if (nl == 0) {
#pragma unroll
            for (int r = 0; r < 4; r++) {
                int n2 = rnode + r;
                if (n2 < N_NODES) { el2[n2] = plv[r]; er2[n2] = prv[r]; }
            }
        }
        // pack bf16x2 into wave-private LDS stripe (no barrier needed)
#pragma unroll
        for (int c = 0; c < 8; c++) {
#pragma unroll
            for (int r = 0; r < 4; r++) {
                float v = acc[c][r];
                float v2 = __shfl_xor(v, 1);
                if (!(lane & 1)) {
                    unsigned u = f2bf(v) | (f2bf(v2) << 16);
                    zt[wid * 16 + kq * 4 + r][c * 8 + (nl >> 1)] = u;
                }
            }
        }
        // flush: 4 passes x (4 rows x 256B) = coalesced full-line dwordx4 stores
#pragma unroll
        for (int pass = 0; pass < 4; pass++) {
            int rl = wid * 16 + pass * 4 + (lane >> 4);
            int n2 = i0 + rl;
            if (n2 < N_NODES) {
                uint4 v = *(const uint4*)&zt[rl][4 * (lane & 15)];
                *(uint4*)&zb[(size_t)n2 * 64 + 4 * (lane & 15)] = v;
            }
        }
    }
}

// --- K7: FUSED layer-2 attention + aggregation, LDS-staged weights ---
__global__ __launch_bounds__(256) void k_l2f(
    const int* __restrict__ offs, const int* __restrict__ csr_src,
    const float* __restrict__ el2, const float* __restrict__ er2,
    const unsigned* __restrict__ zb, const float* __restrict__ b2,
    float* __restrict__ h2) {
    __shared__ float wbuf[4][MAXD];
    __shared__ int   sbuf[4][MAXD];
    int wv = threadIdx.x >> 6;
    int node = blockIdx.x * 4 + wv;
    if (node >= N_NODES) return;
    int l = threadIdx.x & 63;
    float eri = er2[node];
    int off = offs[node], end = offs[node + 1];
    int deg = end - off;
    int ndeg = min(deg, MAXD);
    float mx = -INFINITY;
    for (int j = l; j < deg; j += 64) {
        int s = csr_src[off + j];
        float x = el2[s] + eri;
        float e2 = lrelu(x);
        if (j < MAXD) { sbuf[wv][j] = s; wbuf[wv][j] = e2; }
        mx = fmaxf(mx, e2);
    }
    for (int st = 1; st < 64; st <<= 1) mx = fmaxf(mx, __shfl_xor(mx, st));
    float den = 0.f;
    for (int j = l; j < ndeg; j += 64) {
        float w = __expf(wbuf[wv][j] - mx);
        wbuf[wv][j] = w;
        den += w;
    }
    for (int j = MAXD + l; j < deg; j += 64) {
        int s = csr_src[off + j];
        den += __expf(lrelu(el2[s] + eri) - mx);
    }
    for (int st = 1; st < 64; st <<= 1) den += __shfl_xor(den, st);
    float rden = 1.f / fmaxf(den, 1e-9f);
    float a0 = 0.f, a1 = 0.f;
    int j = 0;
    for (; j + 4 <= ndeg; j += 4) {
        float4 w4 = *(const float4*)&wbuf[wv][j];
        int4   s4 = *(const int4*)&sbuf[wv][j];
        unsigned z0 = zb[((unsigned)s4.x << 6) + l];
        unsigned z1 = zb[((unsigned)s4.y << 6) + l];
        unsigned z2 = zb[((unsigned)s4.z << 6) + l];
        unsigned z3 = zb[((unsigned)s4.w << 6) + l];
        a0 += w4.x * bf_lo(z0) + w4.y * bf_lo(z1) + w4.z * bf_lo(z2) + w4.w * bf_lo(z3);
        a1 += w4.x * bf_hi(z0) + w4.y * bf_hi(z1) + w4.z * bf_hi(z2) + w4.w * bf_hi(z3);
    }
    for (; j < ndeg; j++) {
        float w = wbuf[wv][j];
        unsigned z = zb[((unsigned)sbuf[wv][j] << 6) + l];
        a0 += w * bf_lo(z);
        a1 += w * bf_hi(z);
    }
    for (int j2 = MAXD; j2 < deg; j2++) {
        int s = csr_src[off + j2];
        float w = __expf(lrelu(el2[s] + eri) - mx);
        unsigned z = zb[((unsigned)s << 6) + l];
        a0 += w * bf_lo(z);
        a1 += w * bf_hi(z);
    }
    float2 bb = *(const float2*)&b2[2 * l];
    float2 o;
    o.x = elu_f(a0 * rden + bb.x);
    o.y = elu_f(a1 * rden + bb.y);
    *(float2*)&h2[(size_t)node * HID + 2 * l] = o;
}

// --- K8: mean-pool + classifier ---
static __device__ __forceinline__ int lower_bound_i(const int* a, int n, int v) {
    int lo = 0, hi = n;
    while (lo < hi) { int mid = (lo + hi) >> 1; if (a[mid] < v) lo = mid + 1; else hi = mid; }
    return lo;
}

__global__ __launch_bounds__(1024) void k_pool(const int* __restrict__ gids, const float* __restrict__ h2,
                                               const float* __restrict__ Wc, const float* __restrict__ bc,
                                               float* __restrict__ out) {
    int g = blockIdx.x;
    int lo = lower_bound_i(gids, N_NODES, g);
    int hi = lower_bound_i(gids, N_NODES, g + 1);
    int j = threadIdx.x & 127;
    int nn = threadIdx.x >> 7;
    float s = 0.f;
    for (int n = lo + nn; n < hi; n += 8) s += h2[(size_t)n * HID + j];
    __shared__ float red[1024];
    red[threadIdx.x] = s;
    __syncthreads();
    __shared__ float red2[2][3];
    if (threadIdx.x < 128) {
        float hg = 0.f;
#pragma unroll
        for (int q = 0; q < 8; q++) hg += red[q * 128 + j];
        hg /= fmaxf((float)(hi - lo), 1.f);
        float p0 = hg * Wc[j * 3 + 0];
        float p1 = hg * Wc[j * 3 + 1];
        float p2 = hg * Wc[j * 3 + 2];
        for (int mm = 32; mm >= 1; mm >>= 1) {
            p0 += __shfl_xor(p0, mm); p1 += __shfl_xor(p1, mm); p2 += __shfl_xor(p2, mm);
        }
        if ((threadIdx.x & 63) == 0) {
            int w = threadIdx.x >> 6;
            red2[w][0] = p0; red2[w][1] = p1; red2[w][2] = p2;
        }
    }
    __syncthreads();
    if (threadIdx.x < 3)
        out[g * 3 + threadIdx.x] = red2[0][threadIdx.x] + red2[1][threadIdx.x] + bc[threadIdx.x];
}

extern "C" void kernel_launch(void* const* d_in, const int* in_sizes, int n_in,
                              void* d_out, int out_size, void* d_ws, size_t ws_size,
                              hipStream_t stream) {
    (void)in_sizes; (void)n_in; (void)out_size; (void)ws_size;
    const int* edge_src = (const int*)d_in[0];
    const int* edge_dst = (const int*)d_in[1];
    const int* gids     = (const int*)d_in[2];
    const float* W1  = (const float*)d_in[3];
    const float* al1 = (const float*)d_in[4];
    const float* ar1 = (const float*)d_in[5];
    const float* b1  = (const float*)d_in[6];
    const float* W2  = (const float*)d_in[7];
    const float* al2 = (const float*)d_in[8];
    const float* ar2 = (const float*)d_in[9];
    const float* b2  = (const float*)d_in[10];
    const float* Wc  = (const float*)d_in[11];
    const float* bc  = (const float*)d_in[12];
    float* out = (float*)d_out;

    char* p = (char*)d_ws;
    auto alloc = [&](size_t bytes) -> char* {
        char* r = p;
        p += (bytes + 511) & ~(size_t)511;
        return r;
    };
    int*      dr    = (int*)alloc((size_t)NCLASS * N_NODES * 4);
    int*      base  = (int*)alloc((size_t)NCLASS * N_NODES * 4);
    int*      rank  = (int*)alloc((size_t)N_EDGES * 4);
    int*      offs  = (int*)alloc((size_t)(N_NODES + 1) * 4);
    int*      P     = (int*)alloc((size_t)SNB * 4);
    int*      P2    = (int*)alloc((size_t)SNB * 4);
    float*    scal  = (float*)alloc(64);
    int*      csr   = (int*)alloc((size_t)N_EDGES * 4);
    int*      deg   = (int*)alloc((size_t)N_NODES * 4);
    float*    t     = (float*)alloc((size_t)N_NODES * 4);
    float*    el2   = (float*)alloc((size_t)N_NODES * 4);
    float*    er2   = (float*)alloc((size_t)N_NODES * 4);
    unsigned* zb    = (unsigned*)alloc((size_t)N_NODES * 64 * 4);
    float*    h2    = (float*)alloc((size_t)N_NODES * HID * 4);

    hipMemsetAsync(dr, 0, (size_t)NCLASS * N_NODES * 4, stream);

    k_prep<<<1, 64, 0, stream>>>(W1, al1, ar1, scal);
    k_degrank<<<2048, 256, 0, stream>>>(edge_dst, dr, rank);
    k_sum<<<(N_NODES + 255) / 256, 256, 0, stream>>>(dr, deg);
    k_scan_part<<<SNB, 256, 0, stream>>>(deg, P);
    k_scan_p2<<<1, 64, 0, stream>>>(P, P2, offs);
    k_scan_final<<<SNB, 256, 0, stream>>>(deg, P2, offs);
    k_base<<<(N_NODES + 255) / 256, 256, 0, stream>>>(dr, offs, base);
    k_fill<<<2048, 256, 0, stream>>>(edge_src, edge_dst, base, rank, csr);
    k_l1<<<(N_NODES + 3) / 4, 256, 0, stream>>>(deg, offs, csr, scal, t);
    k_gemm<<<GEMM_GRID, 256, 0, stream>>>(t, W1, b1, W2, al2, ar2, zb, el2, er2);
    k_l2f<<<(N_NODES + 3) / 4, 256, 0, stream>>>(offs, csr, el2, er2, zb, b2, h2);
    k_pool<<<N_GRAPHS, 1024, 0, stream>>>(gids, h2, Wc, bc, out);
}

// Round 13
// 375.641 us; speedup vs baseline: 1.0540x; 1.0540x over previous
//
#include <hip/hip_runtime.h>
#include <cstdint>
#include <cstddef>

#define N_NODES 100000
#define N_EDGES 1600000
#define N_GRAPHS 256
#define HID 128
#define NCLASS 8
#define MAXD 128

#define SCHUNK 2048
#define SNB ((N_NODES + SCHUNK - 1) / SCHUNK)  // 49

static __device__ __forceinline__ float lrelu(float x) { return x >= 0.f ? x : 0.2f * x; }
static __device__ __forceinline__ float elu_f(float x) { return x > 0.f ? x : expm1f(x); }
static __device__ __forceinline__ unsigned f2bf(float x) {  // RNE bf16 (as uint16 in low bits)
    union { float f; unsigned u; } v; v.f = x;
    return (v.u + 0x7FFFu + ((v.u >> 16) & 1u)) >> 16;
}
static __device__ __forceinline__ float bf_lo(unsigned u) { return __uint_as_float(u << 16); }
static __device__ __forceinline__ float bf_hi(unsigned u) { return __uint_as_float(u & 0xFFFF0000u); }

// --- K1: cl1 = W1·al1, cr1 = W1·ar1 (layer-1 rank-1 collapse) ---
__global__ void k_prep(const float* __restrict__ W1, const float* __restrict__ al1,
                       const float* __restrict__ ar1, float* __restrict__ scal) {
    int l = threadIdx.x;  // 64 threads
    float pl = W1[l] * al1[l] + W1[l + 64] * al1[l + 64];
    float pr = W1[l] * ar1[l] + W1[l + 64] * ar1[l + 64];
    for (int m = 32; m >= 1; m >>= 1) { pl += __shfl_xor(pl, m); pr += __shfl_xor(pr, m); }
    if (l == 0) { scal[0] = pl; scal[1] = pr; }
}

// --- K2: degree count into 8 privatized replicas + per-edge rank (ONE atomic pass) ---
__global__ void k_degrank(const int* __restrict__ dst, int* __restrict__ dr,
                          int* __restrict__ rank) {
    int i = blockIdx.x * blockDim.x + threadIdx.x;
    int st = gridDim.x * blockDim.x;
    for (; i < N_EDGES; i += st) {
        int cls = (i >> 8) & (NCLASS - 1);
        rank[i] = atomicAdd(&dr[cls * N_NODES + dst[i]], 1);
    }
}

// --- K2b: total degree = sum of replicas ---
__global__ void k_sum(const int* __restrict__ dr, int* __restrict__ deg) {
    int d = blockIdx.x * blockDim.x + threadIdx.x;
    if (d < N_NODES) {
        int s = 0;
#pragma unroll
        for (int r = 0; r < NCLASS; r++) s += dr[r * N_NODES + d];
        deg[d] = s;
    }
}

// --- K3: exclusive scan of deg -> offsets ---
__global__ void k_scan_part(const int* __restrict__ deg, int* __restrict__ P) {
    __shared__ int sh[256];
    int base = blockIdx.x * SCHUNK + threadIdx.x * 8;
    int s = 0;
#pragma unroll
    for (int e = 0; e < 8; e++) { int idx = base + e; if (idx < N_NODES) s += deg[idx]; }
    sh[threadIdx.x] = s; __syncthreads();
    for (int d = 128; d >= 1; d >>= 1) {
        if (threadIdx.x < d) sh[threadIdx.x] += sh[threadIdx.x + d];
        __syncthreads();
    }
    if (threadIdx.x == 0) P[blockIdx.x] = sh[0];
}

__global__ void k_scan_p2(const int* __restrict__ P, int* __restrict__ P2, int* __restrict__ offs) {
    if (threadIdx.x == 0) {
        int run = 0;
        for (int b = 0; b < SNB; b++) { P2[b] = run; run += P[b]; }
        offs[N_NODES] = run;
    }
}

// --- K3c: scan_final + per-class base fold (k_base merged in) ---
__global__ void k_scan_final(const int* __restrict__ deg, const int* __restrict__ dr,
                             const int* __restrict__ P2, int* __restrict__ offs,
                             int* __restrict__ base) {
    __shared__ int sh[256];
    int bidx = blockIdx.x * SCHUNK + threadIdx.x * 8;
    int loc[8]; int s = 0;
#pragma unroll
    for (int e = 0; e < 8; e++) {
        int idx = bidx + e;
        loc[e] = (idx < N_NODES) ? deg[idx] : 0;
        s += loc[e];
    }
    int own = s;
    sh[threadIdx.x] = s; __syncthreads();
    for (int d = 1; d < 256; d <<= 1) {
        int v = (threadIdx.x >= (unsigned)d) ? sh[threadIdx.x - d] : 0;
        __syncthreads();
        sh[threadIdx.x] += v;
        __syncthreads();
    }
    int run = P2[blockIdx.x] + sh[threadIdx.x] - own;
#pragma unroll
    for (int e = 0; e < 8; e++) {
        int idx = bidx + e;
        if (idx < N_NODES) {
            offs[idx] = run;
            int rb = run;
#pragma unroll
            for (int r = 0; r < NCLASS; r++) { base[r * N_NODES + idx] = rb; rb += dr[r * N_NODES + idx]; }
            run += loc[e];
        }
    }
}

// --- K4: CSR fill — NO atomics ---
__global__ void k_fill(const int* __restrict__ src, const int* __restrict__ dst,
                       const int* __restrict__ base, const int* __restrict__ rank,
                       int* __restrict__ csr) {
    int i = blockIdx.x * blockDim.x + threadIdx.x;
    int st = gridDim.x * blockDim.x;
    for (; i < N_EDGES; i += st) {
        int cls = (i >> 8) & (NCLASS - 1);
        int pos = base[cls * N_NODES + dst[i]] + rank[i];
        csr[pos] = src[i];
    }
}

// --- K5: layer-1 attention -> t[i] (16-LANE group per node: avg degree 16) ---
__global__ __launch_bounds__(256) void k_l1(const int* __restrict__ deg, const int* __restrict__ offs,
                                            const int* __restrict__ csr_src, const float* __restrict__ scal,
                                            float* __restrict__ t) {
    int node = blockIdx.x * 16 + (threadIdx.x >> 4);
    if (node >= N_NODES) return;
    int l = threadIdx.x & 15;
    float cl = scal[0], cr = scal[1];
    float eri = cr * (float)deg[node];
    int off = offs[node], end = offs[node + 1];
    float m = -INFINITY, den = 0.f, num = 0.f;
    for (int e = off + l; e < end; e += 16) {
        int s = csr_src[e];
        float ds = (float)deg[s];
        float e1 = lrelu(cl * ds + eri);
        if (e1 > m) { float c = __expf(m - e1); den *= c; num *= c; m = e1; }
        float w = __expf(e1 - m);
        den += w; num += w * ds;
    }
    // merge online-softmax states across the 16-lane group (xor stays in-group)
    for (int st = 1; st < 16; st <<= 1) {
        float mo = __shfl_xor(m, st);
        float dn = __shfl_xor(den, st);
        float no = __shfl_xor(num, st);
        float mn = fmaxf(m, mo);
        float sa = (m  > -1e37f) ? __expf(m  - mn) : 0.f;
        float sb = (mo > -1e37f) ? __expf(mo - mn) : 0.f;
        den = den * sa + dn * sb;
        num = num * sa + no * sb;
        m = mn;
    }
    if (l == 0) t[node] = num / fmaxf(den, 1e-9f);
}

// --- K6: z2 = elu(t*W1+b1) @ W2 (bf16 out) — r6 fp32 structure (known-good counters) ---
// 8 groups of 32 lanes; each group computes 8 nodes; k-unroll 4, b128 h1s reads.
__global__ __launch_bounds__(256, 2) void k_gemm(
    const float* __restrict__ t, const float* __restrict__ W1, const float* __restrict__ b1,
    const float* __restrict__ W2, const float* __restrict__ al2, const float* __restrict__ ar2,
    unsigned* __restrict__ zb, float* __restrict__ el2, float* __restrict__ er2) {
    __shared__ float h1s[8][8][HID];
    __shared__ float W1s[HID], b1s[HID], al2s[HID], ar2s[HID];
    if (threadIdx.x < HID) {
        W1s[threadIdx.x] = W1[threadIdx.x]; b1s[threadIdx.x] = b1[threadIdx.x];
        al2s[threadIdx.x] = al2[threadIdx.x]; ar2s[threadIdx.x] = ar2[threadIdx.x];
    }
    __syncthreads();
    int g = threadIdx.x >> 5;
    int lt = threadIdx.x & 31;
    const float4* W2v = (const float4*)W2;
    for (int i0 = blockIdx.x * 64; i0 < N_NODES; i0 += gridDim.x * 64) {
        int ibase = i0 + g * 8;
        for (int n = 0; n < 8; n++) {
            int i = ibase + n;
            if (i < N_NODES) {
                float ti = t[i];
                float4 hv;
                hv.x = elu_f(ti * W1s[4 * lt + 0] + b1s[4 * lt + 0]);
                hv.y = elu_f(ti * W1s[4 * lt + 1] + b1s[4 * lt + 1]);
                hv.z = elu_f(ti * W1s[4 * lt + 2] + b1s[4 * lt + 2]);
                hv.w = elu_f(ti * W1s[4 * lt + 3] + b1s[4 * lt + 3]);
                *(float4*)&h1s[g][n][4 * lt] = hv;
            }
        }
        __syncthreads();
        float4 acc[8];
#pragma unroll
        for (int n = 0; n < 8; n++) acc[n] = make_float4(0.f, 0.f, 0.f, 0.f);
        for (int j = 0; j < HID / 4; j++) {  // 4 k's per iter
            float4 w0 = W2v[(4 * j + 0) * 32 + lt];
            float4 w1 = W2v[(4 * j + 1) * 32 + lt];
            float4 w2 = W2v[(4 * j + 2) * 32 + lt];
            float4 w3 = W2v[(4 * j + 3) * 32 + lt];
#pragma unroll
            for (int n = 0; n < 8; n++) {
                float4 hv = *(const float4*)&h1s[g][n][4 * j];  // b128 broadcast
                acc[n].x += hv.x * w0.x + hv.y * w1.x + hv.z * w2.x + hv.w * w3.x;
                acc[n].y += hv.x * w0.y + hv.y * w1.y + hv.z * w2.y + hv.w * w3.y;
                acc[n].z += hv.x * w0.z + hv.y * w1.z + hv.z * w2.z + hv.w * w3.z;
                acc[n].w += hv.x * w0.w + hv.y * w1.w + hv.z * w2.w + hv.w * w3.w;
            }
        }
#pragma unroll
        for (int n = 0; n < 8; n++) {
            int i = ibase + n;
            if (i < N_NODES) {
                float4 a = acc[n];
                uint2 st;
                st.x = f2bf(a.x) | (f2bf(a.y) << 16);
                st.y = f2bf(a.z) | (f2bf(a.w) << 16);
                *(uint2*)&zb[(size_t)i * 64 + 2 * lt] = st;
                float pl = a.x * al2s[4 * lt] + a.y * al2s[4 * lt + 1] +
                           a.z * al2s[4 * lt + 2] + a.w * al2s[4 * lt + 3];
                float pr = a.x * ar2s[4 * lt] + a.y * ar2s[4 * lt + 1] +
                           a.z * ar2s[4 * lt + 2] + a.w * ar2s[4 * lt + 3];
                for (int mm = 16; mm >= 1; mm >>= 1) { pl += __shfl_xor(pl, mm); pr += __shfl_xor(pr, mm); }
                if (lt == 0) { el2[i] = pl; er2[i] = pr; }
            }
        }
        __syncthreads();
    }
}

// --- K7: FUSED layer-2 attention + aggregation, LDS-staged weights ---
__global__ __launch_bounds__(256) void k_l2f(
    const int* __restrict__ offs, const int* __restrict__ csr_src,
    const float* __restrict__ el2, const float* __restrict__ er2,
    const unsigned* __restrict__ zb, const float* __restrict__ b2,
    float* __restrict__ h2) {
    __shared__ float wbuf[4][MAXD];
    __shared__ int   sbuf[4][MAXD];
    int wv = threadIdx.x >> 6;
    int node = blockIdx.x * 4 + wv;
    if (node >= N_NODES) return;
    int l = threadIdx.x & 63;
    float eri = er2[node];
    int off = offs[node], end = offs[node + 1];
    int deg = end - off;
    int ndeg = min(deg, MAXD);
    float mx = -INFINITY;
    for (int j = l; j < deg; j += 64) {
        int s = csr_src[off + j];
        float x = el2[s] + eri;
        float e2 = lrelu(x);
        if (j < MAXD) { sbuf[wv][j] = s; wbuf[wv][j] = e2; }
        mx = fmaxf(mx, e2);
    }
    for (int st = 1; st < 64; st <<= 1) mx = fmaxf(mx, __shfl_xor(mx, st));
    float den = 0.f;
    for (int j = l; j < ndeg; j += 64) {
        float w = __expf(wbuf[wv][j] - mx);
        wbuf[wv][j] = w;
        den += w;
    }
    for (int j = MAXD + l; j < deg; j += 64) {
        int s = csr_src[off + j];
        den += __expf(lrelu(el2[s] + eri) - mx);
    }
    for (int st = 1; st < 64; st <<= 1) den += __shfl_xor(den, st);
    float rden = 1.f / fmaxf(den, 1e-9f);
    float a0 = 0.f, a1 = 0.f;
    int j = 0;
    for (; j + 4 <= ndeg; j += 4) {
        float4 w4 = *(const float4*)&wbuf[wv][j];
        int4   s4 = *(const int4*)&sbuf[wv][j];
        unsigned z0 = zb[((unsigned)s4.x << 6) + l];
        unsigned z1 = zb[((unsigned)s4.y << 6) + l];
        unsigned z2 = zb[((unsigned)s4.z << 6) + l];
        unsigned z3 = zb[((unsigned)s4.w << 6) + l];
        a0 += w4.x * bf_lo(z0) + w4.y * bf_lo(z1) + w4.z * bf_lo(z2) + w4.w * bf_lo(z3);
        a1 += w4.x * bf_hi(z0) + w4.y * bf_hi(z1) + w4.z * bf_hi(z2) + w4.w * bf_hi(z3);
    }
    for (; j < ndeg; j++) {
        float w = wbuf[wv][j];
        unsigned z = zb[((unsigned)sbuf[wv][j] << 6) + l];
        a0 += w * bf_lo(z);
        a1 += w * bf_hi(z);
    }
    for (int j2 = MAXD; j2 < deg; j2++) {
        int s = csr_src[off + j2];
        float w = __expf(lrelu(el2[s] + eri) - mx);
        unsigned z = zb[((unsigned)s << 6) + l];
        a0 += w * bf_lo(z);
        a1 += w * bf_hi(z);
    }
    float2 bb = *(const float2*)&b2[2 * l];
    float2 o;
    o.x = elu_f(a0 * rden + bb.x);
    o.y = elu_f(a1 * rden + bb.y);
    *(float2*)&h2[(size_t)node * HID + 2 * l] = o;
}

// --- K8: mean-pool + classifier ---
static __device__ __forceinline__ int lower_bound_i(const int* a, int n, int v) {
    int lo = 0, hi = n;
    while (lo < hi) { int mid = (lo + hi) >> 1; if (a[mid] < v) lo = mid + 1; else hi = mid; }
    return lo;
}

__global__ __launch_bounds__(1024) void k_pool(const int* __restrict__ gids, const float* __restrict__ h2,
                                               const float* __restrict__ Wc, const float* __restrict__ bc,
                                               float* __restrict__ out) {
    int g = blockIdx.x;
    int lo = lower_bound_i(gids, N_NODES, g);
    int hi = lower_bound_i(gids, N_NODES, g + 1);
    int j = threadIdx.x & 127;
    int nn = threadIdx.x >> 7;
    float s = 0.f;
    for (int n = lo + nn; n < hi; n += 8) s += h2[(size_t)n * HID + j];
    __shared__ float red[1024];
    red[threadIdx.x] = s;
    __syncthreads();
    __shared__ float red2[2][3];
    if (threadIdx.x < 128) {
        float hg = 0.f;
#pragma unroll
        for (int q = 0; q < 8; q++) hg += red[q * 128 + j];
        hg /= fmaxf((float)(hi - lo), 1.f);
        float p0 = hg * Wc[j * 3 + 0];
        float p1 = hg * Wc[j * 3 + 1];
        float p2 = hg * Wc[j * 3 + 2];
        for (int mm = 32; mm >= 1; mm >>= 1) {
            p0 += __shfl_xor(p0, mm); p1 += __shfl_xor(p1, mm); p2 += __shfl_xor(p2, mm);
        }
        if ((threadIdx.x & 63) == 0) {
            int w = threadIdx.x >> 6;
            red2[w][0] = p0; red2[w][1] = p1; red2[w][2] = p2;
        }
    }
    __syncthreads();
    if (threadIdx.x < 3)
        out[g * 3 + threadIdx.x] = red2[0][threadIdx.x] + red2[1][threadIdx.x] + bc[threadIdx.x];
}

extern "C" void kernel_launch(void* const* d_in, const int* in_sizes, int n_in,
                              void* d_out, int out_size, void* d_ws, size_t ws_size,
                              hipStream_t stream) {
    (void)in_sizes; (void)n_in; (void)out_size; (void)ws_size;
    const int* edge_src = (const int*)d_in[0];
    const int* edge_dst = (const int*)d_in[1];
    const int* gids     = (const int*)d_in[2];
    const float* W1  = (const float*)d_in[3];
    const float* al1 = (const float*)d_in[4];
    const float* ar1 = (const float*)d_in[5];
    const float* b1  = (const float*)d_in[6];
    const float* W2  = (const float*)d_in[7];
    const float* al2 = (const float*)d_in[8];
    const float* ar2 = (const float*)d_in[9];
    const float* b2  = (const float*)d_in[10];
    const float* Wc  = (const float*)d_in[11];
    const float* bc  = (const float*)d_in[12];
    float* out = (float*)d_out;

    char* p = (char*)d_ws;
    auto alloc = [&](size_t bytes) -> char* {
        char* r = p;
        p += (bytes + 511) & ~(size_t)511;
        return r;
    };
    int*      dr    = (int*)alloc((size_t)NCLASS * N_NODES * 4);
    int*      base  = (int*)alloc((size_t)NCLASS * N_NODES * 4);
    int*      rank  = (int*)alloc((size_t)N_EDGES * 4);
    int*      offs  = (int*)alloc((size_t)(N_NODES + 1) * 4);
    int*      P     = (int*)alloc((size_t)SNB * 4);
    int*      P2    = (int*)alloc((size_t)SNB * 4);
    float*    scal  = (float*)alloc(64);
    int*      csr   = (int*)alloc((size_t)N_EDGES * 4);
    int*      deg   = (int*)alloc((size_t)N_NODES * 4);
    float*    t     = (float*)alloc((size_t)N_NODES * 4);
    float*    el2   = (float*)alloc((size_t)N_NODES * 4);
    float*    er2   = (float*)alloc((size_t)N_NODES * 4);
    unsigned* zb    = (unsigned*)alloc((size_t)N_NODES * 64 * 4);
    float*    h2    = (float*)alloc((size_t)N_NODES * HID * 4);

    hipMemsetAsync(dr, 0, (size_t)NCLASS * N_NODES * 4, stream);

    k_prep<<<1, 64, 0, stream>>>(W1, al1, ar1, scal);
    k_degrank<<<2048, 256, 0, stream>>>(edge_dst, dr, rank);
    k_sum<<<(N_NODES + 255) / 256, 256, 0, stream>>>(dr, deg);
    k_scan_part<<<SNB, 256, 0, stream>>>(deg, P);
    k_scan_p2<<<1, 64, 0, stream>>>(P, P2, offs);
    k_scan_final<<<SNB, 256, 0, stream>>>(deg, dr, P2, offs, base);
    k_fill<<<2048, 256, 0, stream>>>(edge_src, edge_dst, base, rank, csr);
    k_l1<<<(N_NODES + 15) / 16, 256, 0, stream>>>(deg, offs, csr, scal, t);
    k_gemm<<<(N_NODES + 63) / 64, 256, 0, stream>>>(t, W1, b1, W2, al2, ar2, zb, el2, er2);
    k_l2f<<<(N_NODES + 3) / 4, 256, 0, stream>>>(offs, csr, el2, er2, zb, b2, h2);
    k_pool<<<N_GRAPHS, 1024, 0, stream>>>(gids, h2, Wc, bc, out);
}